// Round 2
// baseline (1431.873 us; speedup 1.0000x reference)
//
#include <hip/hip_runtime.h>

// GridSampler bilinear, align_corners=True, border padding.
// z: [N=8, C=64, IH=256, IW=256] fp32, grid: [N, H=512, W=512, 2] fp32
// out: [N, C, H, W] fp32
//
// Strategy: one thread handles 4 consecutive w positions (16B store) and
// loops over all 64 channels, so the index/weight computation is done once
// per spatial point and amortized over C. Gathers are random within a
// 256 KB (IH*IW*4) plane -> served by L2/L3. Output is streamed with
// nontemporal stores to avoid polluting L2 (we want L2 for z gathers).

constexpr int N  = 8;
constexpr int C  = 64;
constexpr int IH = 256;
constexpr int IW = 256;
constexpr int H  = 512;
constexpr int W  = 512;

typedef float floatx4 __attribute__((ext_vector_type(4)));

__global__ __launch_bounds__(256) void grid_sample_kernel(
    const float* __restrict__ z, const float* __restrict__ grid,
    float* __restrict__ out) {
  // thread -> (n, h, w0) with w0 = 4*wq
  int t  = blockIdx.x * blockDim.x + threadIdx.x;   // 0 .. N*H*W/4 - 1
  int wq = t & (W / 4 - 1);                         // W/4 = 128
  int nh = t >> 7;
  int h  = nh & (H - 1);
  int n  = nh >> 9;
  int w0 = wq << 2;

  const float2* gptr =
      (const float2*)grid + ((size_t)(n * H + h) * W + w0);

  int   i00[4], i01[4], i10[4], i11[4];
  float w00[4], w01[4], w10[4], w11[4];

#pragma unroll
  for (int j = 0; j < 4; ++j) {
    float2 g  = gptr[j];
    float  ix = (g.x + 1.0f) * 0.5f * (IW - 1);
    float  iy = (g.y + 1.0f) * 0.5f * (IH - 1);
    float  fx = floorf(ix);
    float  fy = floorf(iy);
    float  tx = ix - fx;   // in [0,1)
    float  ty = iy - fy;
    w00[j] = (1.0f - tx) * (1.0f - ty);
    w01[j] = tx * (1.0f - ty);
    w10[j] = (1.0f - tx) * ty;
    w11[j] = tx * ty;
    int x0 = min(max((int)fx, 0), IW - 1);
    int x1 = min(max((int)fx + 1, 0), IW - 1);
    int y0 = min(max((int)fy, 0), IH - 1);
    int y1 = min(max((int)fy + 1, 0), IH - 1);
    i00[j] = y0 * IW + x0;
    i01[j] = y0 * IW + x1;
    i10[j] = y1 * IW + x0;
    i11[j] = y1 * IW + x1;
  }

  const float* zn = z + (size_t)n * C * IH * IW;
  float* on = out + (size_t)n * C * H * W + (size_t)h * W + w0;

  for (int c = 0; c < C; ++c) {
    const float* __restrict__ zp = zn + (size_t)c * (IH * IW);
    floatx4 r;
#pragma unroll
    for (int j = 0; j < 4; ++j) {
      r[j] = w00[j] * zp[i00[j]] + w01[j] * zp[i01[j]] +
             w10[j] * zp[i10[j]] + w11[j] * zp[i11[j]];
    }
    __builtin_nontemporal_store(r, (floatx4*)(on + (size_t)c * (H * W)));
  }
}

extern "C" void kernel_launch(void* const* d_in, const int* in_sizes, int n_in,
                              void* d_out, int out_size, void* d_ws,
                              size_t ws_size, hipStream_t stream) {
  const float* z    = (const float*)d_in[0];
  const float* grid = (const float*)d_in[1];
  float*       out  = (float*)d_out;

  int threads = N * H * W / 4;  // 524288
  dim3 block(256);
  dim3 gridDim(threads / 256);  // 2048
  grid_sample_kernel<<<gridDim, block, 0, stream>>>(z, grid, out);
}